// Round 11
// baseline (136.467 us; speedup 1.0000x reference)
//
#include <hip/hip_runtime.h>
#include <hip/hip_bf16.h>
#include <hip/hip_fp16.h>
#include <math.h>

#define NUM_HEADS 6
#define DH 64
#define NSEQ 1024
#define DMODEL 384
#define BBATCH 8
#define WN 147456

typedef __attribute__((ext_vector_type(8))) _Float16 half8;
typedef __attribute__((ext_vector_type(4))) _Float16 half4v;
typedef __attribute__((ext_vector_type(4))) float floatx4;

// ---------------- prep: x, W -> fp16 ----------------
__global__ __launch_bounds__(256) void prep_f16(
    const float* __restrict__ x, const float* __restrict__ Wq,
    const float* __restrict__ Wk, const float* __restrict__ Wv,
    const float* __restrict__ Wp, _Float16* __restrict__ xh,
    _Float16* __restrict__ WH) {
  const int idx = blockIdx.x * 256 + threadIdx.x;
  if (idx < 786432) {
    float4 v = ((const float4*)x)[idx];
    half4v h;
    h[0] = (_Float16)v.x; h[1] = (_Float16)v.y;
    h[2] = (_Float16)v.z; h[3] = (_Float16)v.w;
    ((half4v*)xh)[idx] = h;
  } else {
    int t = idx - 786432;
    int w = t / 36864;
    int rr = t - w * 36864;
    const float* W = (w == 0) ? Wq : (w == 1) ? Wk : (w == 2) ? Wv : Wp;
    float4 v = ((const float4*)W)[rr];
    half4v h;
    h[0] = (_Float16)v.x; h[1] = (_Float16)v.y;
    h[2] = (_Float16)v.z; h[3] = (_Float16)v.w;
    ((half4v*)(WH + (size_t)w * WN))[rr] = h;
  }
}

// ---------------- MFMA NT GEMM: C = A @ W^T, fp16 single-pass (unchanged R10) ----------------
template <int MODE>
__global__ __launch_bounds__(256) void gemm_f16(
    const _Float16* __restrict__ Abf, const _Float16* __restrict__ WH,
    const float* __restrict__ lam_ptr,
    _Float16* __restrict__ qs, _Float16* __restrict__ ks,
    _Float16* __restrict__ vt, float* __restrict__ outp) {
  __shared__ _Float16 sB[2][8192];

  const int tid = threadIdx.x;
  const int wave = tid >> 6;
  const int lane = tid & 63;
  const int quad = lane >> 4;
  const int l16 = lane & 15;

  const int bm = blockIdx.x * 128;
  const int bn = blockIdx.y * 128;
  const int z = (MODE == 0) ? blockIdx.z : 3;

  float cs = 1.0f;
  if (MODE == 0 && z == 0) cs = 0.125f / (1.0f + __expf(-lam_ptr[0]));

  const _Float16* __restrict__ Wsel = WH + (size_t)z * WN;
  const _Float16* srcp[4];
  int dsto[4];
#pragma unroll
  for (int i = 0; i < 4; ++i) {
    const int Gd = i * 256 + tid;
    const int row = Gd >> 3;
    const int g = (Gd & 7) ^ (row & 7);
    srcp[i] = Wsel + (size_t)(bn + row) * DMODEL + g * 8;
    dsto[i] = (i * 256 + wave * 64) * 8;
  }

  const _Float16* aptr[2];
#pragma unroll
  for (int mt = 0; mt < 2; ++mt)
    aptr[mt] = Abf + (size_t)(bm + wave * 32 + mt * 16 + l16) * DMODEL + quad * 8;

  floatx4 acc[2][8];
#pragma unroll
  for (int i = 0; i < 2; ++i)
#pragma unroll
    for (int j = 0; j < 8; ++j) acc[i][j] = (floatx4){0.f, 0.f, 0.f, 0.f};

#pragma unroll
  for (int i = 0; i < 4; ++i)
    __builtin_amdgcn_global_load_lds(
        (const __attribute__((address_space(1))) unsigned*)srcp[i],
        (__attribute__((address_space(3))) unsigned*)(&sB[0][0] + dsto[i]), 16, 0, 0);
  half8 ar[2][2][2];
  ar[0][0][0] = *(const half8*)(aptr[0]);
  ar[0][0][1] = *(const half8*)(aptr[0] + 32);
  ar[0][1][0] = *(const half8*)(aptr[1]);
  ar[0][1][1] = *(const half8*)(aptr[1] + 32);

#pragma unroll
  for (int it = 0; it < 6; ++it) {
    const int cur = it & 1, nxt = cur ^ 1;
    __syncthreads();
    if (it + 1 < 6) {
      const int ko = (it + 1) * 64;
#pragma unroll
      for (int i = 0; i < 4; ++i)
        __builtin_amdgcn_global_load_lds(
            (const __attribute__((address_space(1))) unsigned*)(srcp[i] + ko),
            (__attribute__((address_space(3))) unsigned*)(&sB[nxt][0] + dsto[i]),
            16, 0, 0);
      ar[nxt][0][0] = *(const half8*)(aptr[0] + ko);
      ar[nxt][0][1] = *(const half8*)(aptr[0] + ko + 32);
      ar[nxt][1][0] = *(const half8*)(aptr[1] + ko);
      ar[nxt][1][1] = *(const half8*)(aptr[1] + ko + 32);
    }
#pragma unroll
    for (int nt = 0; nt < 8; ++nt) {
      const int row = nt * 16 + l16;
      half8 bf0 = *(const half8*)&sB[cur][row * 64 + ((quad ^ (row & 7)) << 3)];
      half8 bf1 = *(const half8*)&sB[cur][row * 64 + (((4 + quad) ^ (row & 7)) << 3)];
      acc[0][nt] = __builtin_amdgcn_mfma_f32_16x16x32_f16(ar[cur][0][0], bf0, acc[0][nt], 0, 0, 0);
      acc[0][nt] = __builtin_amdgcn_mfma_f32_16x16x32_f16(ar[cur][0][1], bf1, acc[0][nt], 0, 0, 0);
      acc[1][nt] = __builtin_amdgcn_mfma_f32_16x16x32_f16(ar[cur][1][0], bf0, acc[1][nt], 0, 0, 0);
      acc[1][nt] = __builtin_amdgcn_mfma_f32_16x16x32_f16(ar[cur][1][1], bf1, acc[1][nt], 0, 0, 0);
    }
  }

#pragma unroll
  for (int mt = 0; mt < 2; ++mt) {
    const int m0 = bm + wave * 32 + mt * 16 + quad * 4;
    const int b = m0 >> 10;
    const int n0 = m0 & (NSEQ - 1);
#pragma unroll
    for (int nt = 0; nt < 8; ++nt) {
      const int c = bn + nt * 16 + l16;
      if constexpr (MODE == 0) {
        const int head = c >> 6;
        const int d = c & 63;
        if (z == 2) {
          half4v sv;
          sv[0] = (_Float16)acc[mt][nt][0]; sv[1] = (_Float16)acc[mt][nt][1];
          sv[2] = (_Float16)acc[mt][nt][2]; sv[3] = (_Float16)acc[mt][nt][3];
          *(half4v*)&vt[((size_t)(b * NUM_HEADS + head) * DH + d) * NSEQ + n0] = sv;
        } else {
          _Float16* tgt = z ? ks : qs;
#pragma unroll
          for (int r = 0; r < 4; ++r)
            tgt[((size_t)(b * NUM_HEADS + head) * NSEQ + n0 + r) * DH + d] =
                (_Float16)(acc[mt][nt][r] * cs);
        }
      } else {
#pragma unroll
        for (int r = 0; r < 4; ++r)
          outp[(size_t)(m0 + r) * DMODEL + c] = acc[mt][nt][r];
      }
    }
  }
}

// ---------------- attention: 2-wave blocks, 32 queries/wave ----------------
// 128 thr = 2 waves; wave owns 32 q (2 q-tiles); block = 64 q; grid (48,16) =
// 768 blocks = exactly 3/CU (R10's 384 was 1.5/CU -> 2x imbalance). Same K/V
// LDS reads per wave now feed 2x MFMA -> total LDS-read volume halves (the
// binding resource). 48%8==0 keeps all q-blocks of a bh on one XCD.
__global__ __launch_bounds__(128) void attn_tile(
    const _Float16* __restrict__ qs, const _Float16* __restrict__ ks,
    const _Float16* __restrict__ vt, _Float16* __restrict__ aoh,
    const float* __restrict__ lam_ptr, const float* __restrict__ lsig_ptr) {
  __shared__ _Float16 sK[2][4096];
  __shared__ _Float16 sVT[2][4096];
  __shared__ _Float16 sP[4 * 1024];

  const int tid = threadIdx.x;
  const int wave = tid >> 6;   // 0..1
  const int lane = tid & 63;
  const int quad = lane >> 4;
  const int l16 = lane & 15;
  const int l16a7 = l16 & 7;

  const int bh = blockIdx.x;
  const int qbase = blockIdx.y << 6;   // 64 q per block

  const _Float16* qb = qs + (size_t)bh * NSEQ * DH;
  const _Float16* kb = ks + (size_t)bh * NSEQ * DH;
  const _Float16* vb = vt + (size_t)bh * DH * NSEQ;

  const float lam = 1.0f / (1.0f + __expf(-lam_ptr[0]));
  const float sg = log1pf(__expf(lsig_ptr[0])) + 1e-6f;
  const float ninv2s2 = -1.0f / (2.0f * sg * sg);
  const float pscale = 1.0f - lam;

  // lane-resident Gaussian Et; hoisted Exh[qt][mp][r] (dx chunk-invariant)
  const int la31 = lane & 31;
  const float Etv = __expf(ninv2s2 * (float)(la31 * la31));
  float Exh[2][2][4];
#pragma unroll
  for (int qt = 0; qt < 2; ++qt)
#pragma unroll
    for (int mp = 0; mp < 2; ++mp)
#pragma unroll
      for (int r = 0; r < 4; ++r) {
        const int dx = qt * 16 + l16 - mp * 16 - quad * 4 - r;
        const int idx = dx < 0 ? -dx : dx;
        Exh[qt][mp][r] = __int_as_float(
            __builtin_amdgcn_ds_bpermute(idx << 2, __float_as_int(Etv)));
      }
  const int qy = (qbase >> 5) + wave;  // wave-uniform query grid-row

  // Q B-frags: 2 q-tiles of 16
  half8 aqf[2][2];
#pragma unroll
  for (int qt = 0; qt < 2; ++qt) {
    const int qrow = qbase + wave * 32 + qt * 16 + l16;
    aqf[qt][0] = *(const half8*)&qb[(size_t)qrow * DH + quad * 8];
    aqf[qt][1] = *(const half8*)&qb[(size_t)qrow * DH + 32 + quad * 8];
  }

  // staging: 512 granules K + 512 V per chunk; 4+4 DMA per thread
  const _Float16* srcpK[4];
  const _Float16* srcpV[4];
  int dsto[4];
#pragma unroll
  for (int i = 0; i < 4; ++i) {
    const int G = i * 128 + tid;
    const int row = G >> 3;
    const int g = (G & 7) ^ (row & 7);
    srcpK[i] = kb + (size_t)row * DH + g * 8;
    srcpV[i] = vb + (size_t)row * NSEQ + g * 8;
    dsto[i] = (i * 128 + wave * 64) * 8;  // + HW lane*16B
  }

  floatx4 oacc[2][4];
#pragma unroll
  for (int qt = 0; qt < 2; ++qt)
#pragma unroll
    for (int t = 0; t < 4; ++t) oacc[qt][t] = (floatx4){0.f, 0.f, 0.f, 0.f};
  float plsum[2] = {0.f, 0.f};

#pragma unroll
  for (int i = 0; i < 4; ++i) {
    __builtin_amdgcn_global_load_lds(
        (const __attribute__((address_space(1))) unsigned*)srcpK[i],
        (__attribute__((address_space(3))) unsigned*)(&sK[0][0] + dsto[i]), 16, 0, 0);
    __builtin_amdgcn_global_load_lds(
        (const __attribute__((address_space(1))) unsigned*)srcpV[i],
        (__attribute__((address_space(3))) unsigned*)(&sVT[0][0] + dsto[i]), 16, 0, 0);
  }

  for (int ch = 0; ch < 16; ++ch) {
    __syncthreads();  // DMA(ch) drained; other buf's readers done
    if (ch + 1 < 16) {
      const int nb = (ch + 1) & 1;
#pragma unroll
      for (int i = 0; i < 4; ++i) {
        __builtin_amdgcn_global_load_lds(
            (const __attribute__((address_space(1))) unsigned*)(srcpK[i] + (ch + 1) * 4096),
            (__attribute__((address_space(3))) unsigned*)(&sK[nb][0] + dsto[i]), 16, 0, 0);
        __builtin_amdgcn_global_load_lds(
            (const __attribute__((address_space(1))) unsigned*)(srcpV[i] + (ch + 1) * 64),
            (__attribute__((address_space(3))) unsigned*)(&sVT[nb][0] + dsto[i]), 16, 0, 0);
      }
    }
    const int buf = ch & 1;

    // K A-frags (full 64-key tile)
    half8 kf[4][2];
#pragma unroll
    for (int mt = 0; mt < 4; ++mt) {
      const int row = mt * 16 + l16;
#pragma unroll
      for (int h = 0; h < 2; ++h)
        kf[mt][h] = *(const half8*)&sK[buf][row * 64 + (((h * 4 + quad) ^ (row & 7)) << 3)];
    }

    // positional y-terms
    const float dy0 = (float)(qy - 2 * ch);
    const float dy1 = dy0 - 1.0f;
    float ey[2];
    ey[0] = pscale * __expf(ninv2s2 * dy0 * dy0);
    ey[1] = pscale * __expf(ninv2s2 * dy1 * dy1);

    // S^T per q-tile, exp, packed P store
#pragma unroll
    for (int qt = 0; qt < 2; ++qt) {
#pragma unroll
      for (int mt = 0; mt < 4; ++mt) {
        floatx4 c = {0.f, 0.f, 0.f, 0.f};
        c = __builtin_amdgcn_mfma_f32_16x16x32_f16(kf[mt][0], aqf[qt][0], c, 0, 0, 0);
        c = __builtin_amdgcn_mfma_f32_16x16x32_f16(kf[mt][1], aqf[qt][1], c, 0, 0, 0);
        half4v pk;
#pragma unroll
        for (int r = 0; r < 4; ++r) {
          const float p = __expf(fmaf(ey[mt >> 1], Exh[qt][mt & 1][r], c[r]));
          plsum[qt] += p;
          pk[r] = (_Float16)p;
        }
        const int gg = mt * 4 + quad;
        const int off = (wave * 2 + qt) * 1024 + l16 * 64 +
                        (((gg >> 1) ^ l16a7) << 3) + ((gg & 1) << 2);
        *(half4v*)&sP[off] = pk;
      }
    }

    // P A-frags + PV
#pragma unroll
    for (int qt = 0; qt < 2; ++qt) {
      const int pb = (wave * 2 + qt) * 1024 + l16 * 64;
      half8 pA0 = *(const half8*)&sP[pb + ((quad ^ l16a7) << 3)];
      half8 pA1 = *(const half8*)&sP[pb + (((4 + quad) ^ l16a7) << 3)];
#pragma unroll
      for (int dt = 0; dt < 4; ++dt) {
        const int row = dt * 16 + l16;
        half8 vf0 = *(const half8*)&sVT[buf][row * 64 + ((quad ^ (row & 7)) << 3)];
        half8 vf1 = *(const half8*)&sVT[buf][row * 64 + (((4 + quad) ^ (row & 7)) << 3)];
        oacc[qt][dt] = __builtin_amdgcn_mfma_f32_16x16x32_f16(pA0, vf0, oacc[qt][dt], 0, 0, 0);
        oacc[qt][dt] = __builtin_amdgcn_mfma_f32_16x16x32_f16(pA1, vf1, oacc[qt][dt], 0, 0, 0);
      }
    }
  }

  // denominators: reduce across quads, redistribute to C-layout rows
  const int b = bh / NUM_HEADS, head = bh % NUM_HEADS;
#pragma unroll
  for (int qt = 0; qt < 2; ++qt) {
    float s = plsum[qt];
    s += __shfl_xor(s, 16, 64);
    s += __shfl_xor(s, 32, 64);
    const float inv = 1.0f / s;
    float invr[4];
#pragma unroll
    for (int rr = 0; rr < 4; ++rr)
      invr[rr] = __int_as_float(
          __builtin_amdgcn_ds_bpermute((quad * 4 + rr) << 2, __float_as_int(inv)));
#pragma unroll
    for (int dt = 0; dt < 4; ++dt)
#pragma unroll
      for (int rr = 0; rr < 4; ++rr)
        aoh[(size_t)(b * NSEQ + qbase + wave * 32 + qt * 16 + quad * 4 + rr) * DMODEL +
            head * DH + dt * 16 + l16] = (_Float16)(oacc[qt][dt][rr] * invr[rr]);
  }
}

extern "C" void kernel_launch(void* const* d_in, const int* in_sizes, int n_in,
                              void* d_out, int out_size, void* d_ws, size_t ws_size,
                              hipStream_t stream) {
  const float* x    = (const float*)d_in[0];
  const float* Wq   = (const float*)d_in[1];
  const float* Wk   = (const float*)d_in[2];
  const float* Wv   = (const float*)d_in[3];
  const float* Wp   = (const float*)d_in[4];
  const float* lamp = (const float*)d_in[5];
  const float* lsig = (const float*)d_in[6];
  float* out = (float*)d_out;

  char* ws = (char*)d_ws;
  const size_t NE = (size_t)BBATCH * NSEQ * DMODEL;  // 3,145,728
  _Float16* xh = (_Float16*)ws;      // later reused as attention output
  _Float16* WH = xh + NE;
  _Float16* qs = WH + 4 * (size_t)WN;
  _Float16* ks = qs + NE;
  _Float16* vt = ks + NE;
  _Float16* aoh = xh;                // alias: x no longer needed after QKV

  prep_f16<<<3648, 256, 0, stream>>>(x, Wq, Wk, Wv, Wp, xh, WH);

  dim3 gq(64, 3, 3);
  gemm_f16<0><<<gq, 256, 0, stream>>>(xh, WH, lamp, qs, ks, vt, nullptr);

  attn_tile<<<dim3(48, 16), 128, 0, stream>>>(qs, ks, vt, aoh, lamp, lsig);

  dim3 gp(64, 3);
  gemm_f16<1><<<gp, 256, 0, stream>>>(aoh, WH, lamp, nullptr, nullptr, nullptr, out);
}